// Round 6
// baseline (240.842 us; speedup 1.0000x reference)
//
#include <hip/hip_runtime.h>
#include <stdint.h>

#define H 256
#define EPS 1e-8f

typedef __bf16 bf16x8 __attribute__((ext_vector_type(8)));
typedef float  f32x4  __attribute__((ext_vector_type(4)));

__device__ __forceinline__ unsigned short f2bf(float f) {
  unsigned u = __builtin_bit_cast(unsigned, f);
  u += 0x7FFFu + ((u >> 16) & 1u);            // round-to-nearest-even
  return (unsigned short)(u >> 16);
}
__device__ __forceinline__ float bflo(unsigned u){ return __builtin_bit_cast(float, u << 16); }
__device__ __forceinline__ float bfhi(unsigned u){ return __builtin_bit_cast(float, u & 0xFFFF0000u); }

__device__ __forceinline__ bf16x8 pack8(float4 a, float4 b) {
  uint4 p;
  p.x = (unsigned)f2bf(a.x) | ((unsigned)f2bf(a.y) << 16);
  p.y = (unsigned)f2bf(a.z) | ((unsigned)f2bf(a.w) << 16);
  p.z = (unsigned)f2bf(b.x) | ((unsigned)f2bf(b.y) << 16);
  p.w = (unsigned)f2bf(b.z) | ((unsigned)f2bf(b.w) << 16);
  return __builtin_bit_cast(bf16x8, p);
}

// both 256x256 weight matrices in one launch (grid = 2*H*H/4/256 = 128)
__global__ __launch_bounds__(256) void conv_w_kernel(
    const float* __restrict__ W1, const float* __restrict__ W2,
    unsigned short* __restrict__ w1B, unsigned short* __restrict__ w2B) {
  int i = (blockIdx.x * 256 + threadIdx.x) * 4;
  const int HH = H * H;
  if (i >= 2 * HH) return;
  const float* s = (i < HH) ? W1 : W2;
  unsigned short* d = (i < HH) ? w1B : w2B;
  int j = (i < HH) ? i : i - HH;
  float4 v = *(const float4*)(s + j);
  ushort4 o;
  o.x = f2bf(v.x); o.y = f2bf(v.y); o.z = f2bf(v.z); o.w = f2bf(v.w);
  *(ushort4*)(d + j) = o;
}

// Fused MLP: g = relu(emb@W1^T + b1)@W2^T + b2, plus rn[i] = 1/max(||g_i||,eps).
// Round-6: BARRIER-FREE K-loops. Round-5 counters (MfmaUtil 10.8, VALUBusy 16.4,
// Occ 14.6, all low) showed the __syncthreads vmcnt(0) drain per k-step defeated
// the LDS double-buffer prefetch. Weights are L2-resident (128KB each), so:
//  - W1/W2 fragments load global->VGPR directly (dwordx4, quad-lanes share 64B
//    lines). No sW, no staging barriers.
//  - A fragments load global->VGPR from fp32 emb (float4 x2 + f2bf, bit-identical
//    to the old conv path). No sA. A read exactly once per block.
//  - sH handoff unchanged (m89/m91-verified swapped-GEMM1 layout + XOR swizzle).
//  - Barriers: 2 total (sH handoff, rownorm combine) vs 17 in round-5.
// LDS 32.5KB -> up to 4 blocks/CU (VGPR permitting).
__global__ __launch_bounds__(256) void fused_mlp_kernel(
    const float* __restrict__ Af,           // emb fp32 [N][H]
    const unsigned short* __restrict__ W1,  // [H][H] bf16, row = out-col
    const unsigned short* __restrict__ W2,
    const float* __restrict__ b1, const float* __restrict__ b2,
    unsigned short* __restrict__ G,         // gB out [Mp][H] bf16
    float* __restrict__ rn, int N) {
  __shared__ unsigned short sH[64 * 256];    // 32 KB h (swizzled)
  __shared__ float ssb[64][2];               // rownorm partials per col-half

  const int tid  = threadIdx.x;
  const int wave = tid >> 6, lane = tid & 63;
  const int quad = lane >> 4, l16 = lane & 15;
  const int wr = wave >> 1, wn = wave & 1;
  const size_t bm = blockIdx.x;

  // per-lane A rows (B-operand of swapped GEMM1): two fragments j=0,1
  const int arow0 = (int)bm * 64 + wr * 32 + l16;
  const int arow1 = arow0 + 16;
  const bool v0 = arow0 < N, v1 = arow1 < N;
  const float* pA0 = Af + (size_t)arow0 * H + quad * 8;
  const float* pA1 = Af + (size_t)arow1 * H + quad * 8;
  // per-lane W fragment bases (A-operand): rows wn*128 + i*16 + l16, k = quad*8
  const unsigned short* pW1 = W1 + (size_t)(wn * 128 + l16) * H + quad * 8;
  const unsigned short* pW2 = W2 + (size_t)(wn * 128 + l16) * H + quad * 8;

  // ---------------- GEMM1 (swapped): acc[iC][jR] = h^T subtiles -------------
  f32x4 acc[8][2];
#pragma unroll
  for (int i = 0; i < 8; i++)
#pragma unroll
    for (int j = 0; j < 2; j++) acc[i][j] = (f32x4){0.f, 0.f, 0.f, 0.f};

  const float4 z4 = make_float4(0.f, 0.f, 0.f, 0.f);
#pragma unroll
  for (int kt = 0; kt < 8; ++kt) {
    const int k0 = kt * 32;
    bf16x8 wf[8];
#pragma unroll
    for (int i = 0; i < 8; i++)
      wf[i] = *(const bf16x8*)(pW1 + (size_t)(i * 16) * H + k0);
    float4 a00 = v0 ? *(const float4*)(pA0 + k0)     : z4;
    float4 a01 = v0 ? *(const float4*)(pA0 + k0 + 4) : z4;
    float4 a10 = v1 ? *(const float4*)(pA1 + k0)     : z4;
    float4 a11 = v1 ? *(const float4*)(pA1 + k0 + 4) : z4;
    bf16x8 af0 = pack8(a00, a01);
    bf16x8 af1 = pack8(a10, a11);
#pragma unroll
    for (int i = 0; i < 8; i++) {
      acc[i][0] = __builtin_amdgcn_mfma_f32_16x16x32_bf16(wf[i], af0, acc[i][0], 0, 0, 0);
      acc[i][1] = __builtin_amdgcn_mfma_f32_16x16x32_bf16(wf[i], af1, acc[i][1], 0, 0, 0);
    }
  }

  // ------------- h epilogue: +b1, relu, bf16, packed b64 into sH ------------
  // layout (m89/m91-verified, rounds 4/5 passed): lane l16 = h-row, reg = h-col
#pragma unroll
  for (int i = 0; i < 8; i++) {
    const int hcol = wn * 128 + i * 16 + quad * 4;
    const float4 bv = *(const float4*)(b1 + hcol);
#pragma unroll
    for (int j = 0; j < 2; j++) {
      const int row = wr * 32 + j * 16 + l16;
      f32x4 v = acc[i][j];
      unsigned short h0 = f2bf(fmaxf(v[0] + bv.x, 0.f));
      unsigned short h1 = f2bf(fmaxf(v[1] + bv.y, 0.f));
      unsigned short h2 = f2bf(fmaxf(v[2] + bv.z, 0.f));
      unsigned short h3 = f2bf(fmaxf(v[3] + bv.w, 0.f));
      uint2 p;
      p.x = (unsigned)h0 | ((unsigned)h1 << 16);
      p.y = (unsigned)h2 | ((unsigned)h3 << 16);
      unsigned off = (unsigned)(row * 512 + hcol * 2) ^ ((unsigned)(row & 7) << 4);
      *(uint2*)((char*)sH + off) = p;
    }
  }

  __syncthreads();   // barrier 1: sH visible to the wn-pair

  // ---------------- GEMM2 (normal): acc2[iR][j] = g subtiles ----------------
  f32x4 acc2[2][8];
#pragma unroll
  for (int i = 0; i < 2; i++)
#pragma unroll
    for (int j = 0; j < 8; j++) acc2[i][j] = (f32x4){0.f, 0.f, 0.f, 0.f};

#pragma unroll
  for (int kt = 0; kt < 8; ++kt) {
    bf16x8 wf2[8];
#pragma unroll
    for (int j = 0; j < 8; j++)
      wf2[j] = *(const bf16x8*)(pW2 + (size_t)(j * 16) * H + kt * 32);
    bf16x8 hf[2];
#pragma unroll
    for (int i = 0; i < 2; i++) {
      const int hrow = wr * 32 + i * 16 + l16;
      unsigned off = (unsigned)(hrow * 512 + kt * 64 + quad * 16) ^ ((unsigned)(hrow & 7) << 4);
      hf[i] = *(const bf16x8*)((const char*)sH + off);
    }
#pragma unroll
    for (int i = 0; i < 2; i++)
#pragma unroll
      for (int j = 0; j < 8; j++)
        acc2[i][j] = __builtin_amdgcn_mfma_f32_16x16x32_bf16(hf[i], wf2[j], acc2[i][j], 0, 0, 0);
  }

  // --------- final epilogue: +b2, rownorm (in-block), bf16 g writes ---------
  float b2v[8];
#pragma unroll
  for (int j = 0; j < 8; j++) b2v[j] = b2[wn * 128 + j * 16 + l16];
#pragma unroll
  for (int i = 0; i < 2; i++)
#pragma unroll
    for (int j = 0; j < 8; j++)
#pragma unroll
      for (int r = 0; r < 4; r++) acc2[i][j][r] += b2v[j];

  float ss[2][4];
#pragma unroll
  for (int i = 0; i < 2; i++)
#pragma unroll
    for (int r = 0; r < 4; r++) {
      float s = 0.f;
#pragma unroll
      for (int j = 0; j < 8; j++) s += acc2[i][j][r] * acc2[i][j][r];
      ss[i][r] = s;
    }
#pragma unroll
  for (int m = 1; m < 16; m <<= 1)
#pragma unroll
    for (int i = 0; i < 2; i++)
#pragma unroll
      for (int r = 0; r < 4; r++) ss[i][r] += __shfl_xor(ss[i][r], m, 64);
  if (l16 == 0) {
#pragma unroll
    for (int i = 0; i < 2; i++)
#pragma unroll
      for (int r = 0; r < 4; r++) ssb[wr * 32 + i * 16 + quad * 4 + r][wn] = ss[i][r];
  }
  __syncthreads();   // barrier 2: rownorm combine
  if (tid < 64) {
    float s2 = ssb[tid][0] + ssb[tid][1];
    rn[bm * 64 + tid] = 1.f / fmaxf(sqrtf(s2), EPS);
  }

#pragma unroll
  for (int i = 0; i < 2; i++)
#pragma unroll
    for (int j = 0; j < 8; j++) {
      const int gcol = wn * 128 + j * 16 + l16;
#pragma unroll
      for (int r = 0; r < 4; r++) {
        const size_t grow = bm * 64 + wr * 32 + i * 16 + quad * 4 + r;
        G[grow * H + gcol] = f2bf(acc2[i][j][r]);
      }
    }
}

__device__ __forceinline__ float dot_u4(uint4 a, uint4 b) {
  float s;
  s  = bflo(a.x) * bflo(b.x) + bfhi(a.x) * bfhi(b.x);
  s += bflo(a.y) * bflo(b.y) + bfhi(a.y) * bfhi(b.y);
  s += bflo(a.z) * bflo(b.z) + bfhi(a.z) * bfhi(b.z);
  s += bflo(a.w) * bflo(b.w) + bfhi(a.w) * bfhi(b.w);
  return s;
}

// 8 lanes per edge, 8 edges per wave, 32 edges per block.
__global__ __launch_bounds__(256) void edge_cos_kernel(
    const int* __restrict__ ei, const unsigned short* __restrict__ g,
    const float* __restrict__ rn, float* __restrict__ out, int E) {
  const int lane = threadIdx.x & 63;
  const int wid  = threadIdx.x >> 6;
  const int l8   = lane & 7;
  const int sub  = lane >> 3;
  const int e    = blockIdx.x * 32 + wid * 8 + sub;
  if (e >= E) return;
  const int c = ei[e], r = ei[E + e];
  const uint4* gc = (const uint4*)(g + (size_t)c * H);
  const uint4* gr = (const uint4*)(g + (size_t)r * H);
  uint4 a0 = gc[l8], a1 = gc[l8 + 8], a2 = gc[l8 + 16], a3 = gc[l8 + 24];
  uint4 b0 = gr[l8], b1 = gr[l8 + 8], b2 = gr[l8 + 16], b3 = gr[l8 + 24];
  float d = dot_u4(a0, b0) + dot_u4(a1, b1) + dot_u4(a2, b2) + dot_u4(a3, b3);
  d += __shfl_xor(d, 4, 8);
  d += __shfl_xor(d, 2, 8);
  d += __shfl_xor(d, 1, 8);
  if (l8 == 0) out[e] = d * rn[c] * rn[r];
}

extern "C" void kernel_launch(void* const* d_in, const int* in_sizes, int n_in,
                              void* d_out, int out_size, void* d_ws, size_t ws_size,
                              hipStream_t stream) {
  const float* emb = (const float*)d_in[0];
  const int*   ei  = (const int*)d_in[1];
  const float* W1  = (const float*)d_in[2];
  const float* b1  = (const float*)d_in[3];
  const float* W2  = (const float*)d_in[4];
  const float* b2  = (const float*)d_in[5];
  float* out = (float*)d_out;

  const int NH = in_sizes[0];              // N*H
  const int N  = NH / H;                   // 50000
  const int E  = in_sizes[1] / 2;          // 300000
  const int Mp = ((N + 63) / 64) * 64;     // 50048 (multiple of 64)

  char* ws = (char*)d_ws;
  unsigned short* gB   = (unsigned short*)ws; ws += (size_t)Mp * H * 2;
  unsigned short* w1B  = (unsigned short*)ws; ws += (size_t)H * H * 2;
  unsigned short* w2B  = (unsigned short*)ws; ws += (size_t)H * H * 2;
  float* rn            = (float*)ws;

  conv_w_kernel<<<(2 * H * H / 4 + 255) / 256, 256, 0, stream>>>(W1, W2, w1B, w2B);

  fused_mlp_kernel<<<Mp / 64, 256, 0, stream>>>(emb, w1B, w2B, b1, b2, gB, rn, N);

  edge_cos_kernel<<<(E + 31) / 32, 256, 0, stream>>>(ei, gB, rn, out, E);
}

// Round 8
// 158.244 us; speedup vs baseline: 1.5220x; 1.5220x over previous
//
#include <hip/hip_runtime.h>
#include <stdint.h>

#define H 256
#define EPS 1e-8f

typedef __bf16 bf16x8 __attribute__((ext_vector_type(8)));
typedef float  f32x4  __attribute__((ext_vector_type(4)));

__device__ __forceinline__ unsigned short f2bf(float f) {
  unsigned u = __builtin_bit_cast(unsigned, f);
  u += 0x7FFFu + ((u >> 16) & 1u);            // round-to-nearest-even
  return (unsigned short)(u >> 16);
}
__device__ __forceinline__ float bflo(unsigned u){ return __builtin_bit_cast(float, u << 16); }
__device__ __forceinline__ float bfhi(unsigned u){ return __builtin_bit_cast(float, u & 0xFFFF0000u); }

__device__ __forceinline__ void g2l16(const void* g, void* l) {
  __builtin_amdgcn_global_load_lds((__attribute__((address_space(1))) void*)g,
                                   (__attribute__((address_space(3))) void*)l, 16, 0, 0);
}

// both 256x256 weight matrices in one launch (grid = 2*H*H/4/256 = 128)
__global__ __launch_bounds__(256) void conv_w_kernel(
    const float* __restrict__ W1, const float* __restrict__ W2,
    unsigned short* __restrict__ w1B, unsigned short* __restrict__ w2B) {
  int i = (blockIdx.x * 256 + threadIdx.x) * 4;
  const int HH = H * H;
  if (i >= 2 * HH) return;
  const float* s = (i < HH) ? W1 : W2;
  unsigned short* d = (i < HH) ? w1B : w2B;
  int j = (i < HH) ? i : i - HH;
  float4 v = *(const float4*)(s + j);
  ushort4 o;
  o.x = f2bf(v.x); o.y = f2bf(v.y); o.z = f2bf(v.z); o.w = f2bf(v.w);
  *(ushort4*)(d + j) = o;
}

// Fused MLP: g = relu(emb@W1^T + b1)@W2^T + b2, plus rn[i] = 1/max(||g_i||,eps).
// Round-8 resubmit of round-6 source (never measured; broker failed twice).
// = round-5 structure (43.3us, passed) + counted-vmcnt barriers (T4).
// GEMM1 k-step: STAGE_W(kt+1) [4x g2l16, issued FIRST] ; LOAD_A(kt+2) [2x float4,
// unconditional via row-clamp so vmcnt count is wave-uniform] ; ds_read frags(kt) ;
// WRITE_A(kt+1) ; 16x MFMA ; then "s_waitcnt vmcnt(2) lgkmcnt(0)" + raw s_barrier:
// retires exactly the W stage, keeps the 2 newest A loads in flight ACROSS the
// barrier (__syncthreads would drain them -> that was round-5's stall).
// LDS 8+32+32+0.5 = 72.5 KB -> 2 blocks/CU.
__global__ __launch_bounds__(256) void fused_mlp_kernel(
    const float* __restrict__ Af,           // emb fp32 [N][H]
    const unsigned short* __restrict__ W1,  // [H][H] bf16, row = out-col
    const unsigned short* __restrict__ W2,
    const float* __restrict__ b1, const float* __restrict__ b2,
    unsigned short* __restrict__ G,         // gB out [Mp][H] bf16
    float* __restrict__ rn, int N) {
  __shared__ unsigned short sA[2][64 * 32];   // 8 KB  emb tile (dbuf)
  __shared__ unsigned short sW[2][256 * 32];  // 32 KB weight tile (dbuf, W1 then W2)
  __shared__ unsigned short sH[64 * 256];     // 32 KB h (swizzled)
  __shared__ float ssb[64][2];                // rownorm partials per col-half

  const int tid  = threadIdx.x;
  const int wave = tid >> 6, lane = tid & 63;
  const int quad = lane >> 4, l16 = lane & 15;
  const int wr = wave >> 1, wn = wave & 1;
  const size_t bm = blockIdx.x;

  // staging geometry: thread -> (row, 8-elem k-chunk); sA/sW are row-major [r][32]
  const int arow = tid >> 2, kch = (tid & 3) * 8;
  const int grow = (int)bm * 64 + arow;
  const bool avalid = grow < N;
  const int crow = avalid ? grow : (N - 1);   // clamp: load is ALWAYS issued
  const float* gAf = Af + (size_t)crow * H + kch;
  const unsigned short* gW1 = W1 + (size_t)arow * H + kch;
  const unsigned short* gW2 = W2 + (size_t)arow * H + kch;

  const float4 z4 = make_float4(0.f, 0.f, 0.f, 0.f);
  float4 ra[2][2];
  // unconditional loads -> every wave issues the same VMEM op count (vmcnt-safe)
#define LOAD_A(kt, slot)                                                        \
  do {                                                                          \
    ra[slot][0] = *(const float4*)(gAf + (kt) * 32);                            \
    ra[slot][1] = *(const float4*)(gAf + (kt) * 32 + 4);                        \
  } while (0)
#define WRITE_A(buf, slot)                                                      \
  do {                                                                          \
    float4 t0 = avalid ? ra[slot][0] : z4;                                      \
    float4 t1 = avalid ? ra[slot][1] : z4;                                      \
    uint4 p;                                                                    \
    p.x = (unsigned)f2bf(t0.x) | ((unsigned)f2bf(t0.y) << 16);                  \
    p.y = (unsigned)f2bf(t0.z) | ((unsigned)f2bf(t0.w) << 16);                  \
    p.z = (unsigned)f2bf(t1.x) | ((unsigned)f2bf(t1.y) << 16);                  \
    p.w = (unsigned)f2bf(t1.z) | ((unsigned)f2bf(t1.w) << 16);                  \
    *(uint4*)(&sA[buf][tid * 8]) = p;                                           \
  } while (0)
#define STAGE_W(gW, kt, buf)                                                    \
  do {                                                                          \
    _Pragma("unroll")                                                           \
    for (int c = 0; c < 4; c++)                                                 \
      g2l16((gW) + (size_t)(c * 64) * H + (kt) * 32, &sW[buf][c * 2048 + tid * 8]); \
  } while (0)

  // ---------------- GEMM1 (swapped): acc[iC][jR] = h^T subtiles -------------
  f32x4 acc[8][2];
#pragma unroll
  for (int i = 0; i < 8; i++)
#pragma unroll
    for (int j = 0; j < 2; j++) acc[i][j] = (f32x4){0.f, 0.f, 0.f, 0.f};

  // prologue: W(0) first, then A(0),A(1); WRITE_A(0) forces A(0) (and W) done
  STAGE_W(gW1, 0, 0);
  LOAD_A(0, 0);
  LOAD_A(1, 1);
  WRITE_A(0, 0);
  asm volatile("s_waitcnt vmcnt(2) lgkmcnt(0)" ::: "memory");  // W(0) done, A(1) in flight
  __builtin_amdgcn_s_barrier();

#pragma unroll
  for (int kt = 0; kt < 8; ++kt) {
    if (kt < 7) STAGE_W(gW1, kt + 1, (kt + 1) & 1);   // W(kt+1), issued FIRST
    else        STAGE_W(gW2, 0, 0);                    // W2 tile 0 into freed buf0
    if (kt < 6) LOAD_A(kt + 2, kt & 1);                // A(kt+2) -> slot kt&1

    bf16x8 wf[8], af0, af1;
#pragma unroll
    for (int i = 0; i < 8; i++)
      wf[i] = *(const bf16x8*)(&sW[kt & 1][(wn * 128 + i * 16 + l16) * 32 + quad * 8]);
    af0 = *(const bf16x8*)(&sA[kt & 1][(wr * 32 + 0 * 16 + l16) * 32 + quad * 8]);
    af1 = *(const bf16x8*)(&sA[kt & 1][(wr * 32 + 1 * 16 + l16) * 32 + quad * 8]);

    if (kt < 7) WRITE_A((kt + 1) & 1, (kt + 1) & 1);   // cvt + ds_write next A

#pragma unroll
    for (int i = 0; i < 8; i++) {
      acc[i][0] = __builtin_amdgcn_mfma_f32_16x16x32_bf16(wf[i], af0, acc[i][0], 0, 0, 0);
      acc[i][1] = __builtin_amdgcn_mfma_f32_16x16x32_bf16(wf[i], af1, acc[i][1], 0, 0, 0);
    }

    if (kt < 7) {
      // counted barrier: W(kt+1) retired; (kt<6) the 2 newest A loads stay in flight
      if (kt < 6) asm volatile("s_waitcnt vmcnt(2) lgkmcnt(0)" ::: "memory");
      else        asm volatile("s_waitcnt vmcnt(0) lgkmcnt(0)" ::: "memory");
      __builtin_amdgcn_s_barrier();
    }
    // kt==7: no barrier — W2(0) drains under the h-epilogue, __syncthreads below
  }

  // ------------- h epilogue: +b1, relu, bf16, packed b64 into sH ------------
  // layout (m89/m91-verified, rounds 4/5 passed): lane l16 = h-row, reg = h-col
#pragma unroll
  for (int i = 0; i < 8; i++) {
    const int hcol = wn * 128 + i * 16 + quad * 4;
    const float4 bv = *(const float4*)(b1 + hcol);
#pragma unroll
    for (int j = 0; j < 2; j++) {
      const int row = wr * 32 + j * 16 + l16;
      f32x4 v = acc[i][j];
      unsigned short h0 = f2bf(fmaxf(v[0] + bv.x, 0.f));
      unsigned short h1 = f2bf(fmaxf(v[1] + bv.y, 0.f));
      unsigned short h2 = f2bf(fmaxf(v[2] + bv.z, 0.f));
      unsigned short h3 = f2bf(fmaxf(v[3] + bv.w, 0.f));
      uint2 p;
      p.x = (unsigned)h0 | ((unsigned)h1 << 16);
      p.y = (unsigned)h2 | ((unsigned)h3 << 16);
      unsigned off = (unsigned)(row * 512 + hcol * 2) ^ ((unsigned)(row & 7) << 4);
      *(uint2*)((char*)sH + off) = p;
    }
  }

  __syncthreads();   // sH visible; W2(0) drained (full vmcnt(0) here is fine)

  // ---------------- GEMM2 (normal): acc2[iR][j] = g subtiles ----------------
  f32x4 acc2[2][8];
#pragma unroll
  for (int i = 0; i < 2; i++)
#pragma unroll
    for (int j = 0; j < 8; j++) acc2[i][j] = (f32x4){0.f, 0.f, 0.f, 0.f};

#pragma unroll
  for (int kt = 0; kt < 8; ++kt) {
    if (kt < 7) STAGE_W(gW2, kt + 1, (kt + 1) & 1);    // issued a full step early

    bf16x8 wf2[8], hf[2];
#pragma unroll
    for (int j = 0; j < 8; j++)
      wf2[j] = *(const bf16x8*)(&sW[kt & 1][(wn * 128 + j * 16 + l16) * 32 + quad * 8]);
#pragma unroll
    for (int i = 0; i < 2; i++) {
      const int hrow = wr * 32 + i * 16 + l16;
      unsigned off = (unsigned)(hrow * 512 + kt * 64 + quad * 16) ^ ((unsigned)(hrow & 7) << 4);
      hf[i] = *(const bf16x8*)((const char*)sH + off);
    }
#pragma unroll
    for (int i = 0; i < 2; i++)
#pragma unroll
      for (int j = 0; j < 8; j++)
        acc2[i][j] = __builtin_amdgcn_mfma_f32_16x16x32_bf16(hf[i], wf2[j], acc2[i][j], 0, 0, 0);
    if (kt < 7) __syncthreads();
  }

  // --------- final epilogue: +b2, rownorm (in-block), bf16 g writes ---------
  float b2v[8];
#pragma unroll
  for (int j = 0; j < 8; j++) b2v[j] = b2[wn * 128 + j * 16 + l16];
#pragma unroll
  for (int i = 0; i < 2; i++)
#pragma unroll
    for (int j = 0; j < 8; j++)
#pragma unroll
      for (int r = 0; r < 4; r++) acc2[i][j][r] += b2v[j];

  float ss[2][4];
#pragma unroll
  for (int i = 0; i < 2; i++)
#pragma unroll
    for (int r = 0; r < 4; r++) {
      float s = 0.f;
#pragma unroll
      for (int j = 0; j < 8; j++) s += acc2[i][j][r] * acc2[i][j][r];
      ss[i][r] = s;
    }
#pragma unroll
  for (int m = 1; m < 16; m <<= 1)
#pragma unroll
    for (int i = 0; i < 2; i++)
#pragma unroll
      for (int r = 0; r < 4; r++) ss[i][r] += __shfl_xor(ss[i][r], m, 64);
  if (l16 == 0) {
#pragma unroll
    for (int i = 0; i < 2; i++)
#pragma unroll
      for (int r = 0; r < 4; r++) ssb[wr * 32 + i * 16 + quad * 4 + r][wn] = ss[i][r];
  }
  __syncthreads();   // rownorm combine
  if (tid < 64) {
    float s2 = ssb[tid][0] + ssb[tid][1];
    rn[bm * 64 + tid] = 1.f / fmaxf(sqrtf(s2), EPS);
  }

#pragma unroll
  for (int i = 0; i < 2; i++)
#pragma unroll
    for (int j = 0; j < 8; j++) {
      const int gcol = wn * 128 + j * 16 + l16;
#pragma unroll
      for (int r = 0; r < 4; r++) {
        const size_t grow2 = bm * 64 + wr * 32 + i * 16 + quad * 4 + r;
        G[grow2 * H + gcol] = f2bf(acc2[i][j][r]);
      }
    }
#undef LOAD_A
#undef WRITE_A
#undef STAGE_W
}

__device__ __forceinline__ float dot_u4(uint4 a, uint4 b) {
  float s;
  s  = bflo(a.x) * bflo(b.x) + bfhi(a.x) * bfhi(b.x);
  s += bflo(a.y) * bflo(b.y) + bfhi(a.y) * bfhi(b.y);
  s += bflo(a.z) * bflo(b.z) + bfhi(a.z) * bfhi(b.z);
  s += bflo(a.w) * bflo(b.w) + bfhi(a.w) * bfhi(b.w);
  return s;
}

// 8 lanes per edge, 8 edges per wave, 32 edges per block.
__global__ __launch_bounds__(256) void edge_cos_kernel(
    const int* __restrict__ ei, const unsigned short* __restrict__ g,
    const float* __restrict__ rn, float* __restrict__ out, int E) {
  const int lane = threadIdx.x & 63;
  const int wid  = threadIdx.x >> 6;
  const int l8   = lane & 7;
  const int sub  = lane >> 3;
  const int e    = blockIdx.x * 32 + wid * 8 + sub;
  if (e >= E) return;
  const int c = ei[e], r = ei[E + e];
  const uint4* gc = (const uint4*)(g + (size_t)c * H);
  const uint4* gr = (const uint4*)(g + (size_t)r * H);
  uint4 a0 = gc[l8], a1 = gc[l8 + 8], a2 = gc[l8 + 16], a3 = gc[l8 + 24];
  uint4 b0 = gr[l8], b1 = gr[l8 + 8], b2 = gr[l8 + 16], b3 = gr[l8 + 24];
  float d = dot_u4(a0, b0) + dot_u4(a1, b1) + dot_u4(a2, b2) + dot_u4(a3, b3);
  d += __shfl_xor(d, 4, 8);
  d += __shfl_xor(d, 2, 8);
  d += __shfl_xor(d, 1, 8);
  if (l8 == 0) out[e] = d * rn[c] * rn[r];
}

extern "C" void kernel_launch(void* const* d_in, const int* in_sizes, int n_in,
                              void* d_out, int out_size, void* d_ws, size_t ws_size,
                              hipStream_t stream) {
  const float* emb = (const float*)d_in[0];
  const int*   ei  = (const int*)d_in[1];
  const float* W1  = (const float*)d_in[2];
  const float* b1  = (const float*)d_in[3];
  const float* W2  = (const float*)d_in[4];
  const float* b2  = (const float*)d_in[5];
  float* out = (float*)d_out;

  const int NH = in_sizes[0];              // N*H
  const int N  = NH / H;                   // 50000
  const int E  = in_sizes[1] / 2;          // 300000
  const int Mp = ((N + 63) / 64) * 64;     // 50048 (multiple of 64)

  char* ws = (char*)d_ws;
  unsigned short* gB   = (unsigned short*)ws; ws += (size_t)Mp * H * 2;
  unsigned short* w1B  = (unsigned short*)ws; ws += (size_t)H * H * 2;
  unsigned short* w2B  = (unsigned short*)ws; ws += (size_t)H * H * 2;
  float* rn            = (float*)ws;

  conv_w_kernel<<<(2 * H * H / 4 + 255) / 256, 256, 0, stream>>>(W1, W2, w1B, w2B);

  fused_mlp_kernel<<<Mp / 64, 256, 0, stream>>>(emb, w1B, w2B, b1, b2, gB, rn, N);

  edge_cos_kernel<<<(E + 31) / 32, 256, 0, stream>>>(ei, gB, rn, out, E);
}